// Round 3
// baseline (88.312 us; speedup 1.0000x reference)
//
#include <hip/hip_runtime.h>

// PhysicalCircleLayer on MI355X — round 3.
// One block per batch (B=1024), 256 threads. Key change vs round 2: the
// 2500-float4 sweep is restructured to a CONSTANT 10 trips/thread
// (9 guaranteed + 1 predicated by address clamp + zero-mask), fully
// unrolled, with all 10 coalesced global_load_dwordx4 issued before any
// processing — 10 loads in flight per wave instead of 1 (latency -> BW bound).
//
// Exactness (tracks fp32 numpy reference bit-for-bit, rounds 1-2 absmax 0.0):
//  - (pix-b)/W precomputed in LDS with IEEE '/' (100 distinct values/axis).
//  - moving_vector = (t7+cp)-(t0+cp) in that order; _rn ops block fma fusion.
//  - d2 = add_rn(row_term^2, col_term^2); fp32 add commutative -> unchanged
//    under the order0==1 axis swap (swap only affects bin geometry, exact).
//  - Light path prefilter d2 <= r^2*(1+2e-5) is conservative (no valid pixel
//    skipped); heavy path redoes the exact sqrt(d2) <= r test.
//  - Masked tail lanes load a clamped in-bounds address and force map=0
//    (-> !valid -> INFV contribution), identical to not processing them.

#define INFV 1.0e9f

__global__ __launch_bounds__(256)
void pcl_kernel(const float* __restrict__ seg_maps,
                const float* __restrict__ paras,
                const float* __restrict__ traj,
                const float* __restrict__ cpos,
                float* __restrict__ out)
{
    const int b    = blockIdx.x;
    const int tid  = threadIdx.x;
    const int lane = tid & 63;
    const int wave = tid >> 6;

    __shared__ __align__(16) float sRow[100];    // row-axis term (x if !swp, y if swp)
    __shared__ __align__(16) float sCol[100];    // col-axis term (y if !swp, x if swp)
    __shared__ __align__(16) float sCol2[100];   // mul_rn(col term, col term)
    __shared__ float sred[4][8];

    const float* pp = paras + b * 6;
    const float W0 = pp[0], W1 = pp[1];
    const float bb0 = pp[2], bb1 = pp[3];
    const bool  swp = (pp[4] == 1.0f);
    const float cp0 = cpos[b * 2 + 0];
    const float cp1 = cpos[b * 2 + 1];

    // moving_length: _obs = traj + cp in fp32 BEFORE the subtraction.
    const float* tp  = traj + b * 16;
    const float o00 = __fadd_rn(tp[0],  cp0);
    const float o01 = __fadd_rn(tp[1],  cp1);
    const float o70 = __fadd_rn(tp[14], cp0);
    const float o71 = __fadd_rn(tp[15], cp1);
    const float mv0 = __fsub_rn(o70, o00);
    const float mv1 = __fsub_rn(o71, o01);
    const float mlen = sqrtf(__fadd_rn(__fmul_rn(mv0, mv0), __fmul_rn(mv1, mv1)));
    const float r    = __fmul_rn(2.0f, mlen);
    // conservative prefilter radius^2 (margin >> 6e-7 relative, + tiny abs for r==0)
    const float r2m  = __fmul_rn(r, r) * 1.00002f + 1e-30f;

    if (tid < 100) {
        const float a = ((float)tid - bb0) / W0;          // IEEE divide, matches ref
        sRow[tid] = __fsub_rn(a, swp ? cp1 : cp0);
    } else if (tid < 200) {
        const int j = tid - 100;
        const float c = ((float)j - bb1) / W1;            // IEEE divide, matches ref
        const float cv = __fsub_rn(c, swp ? cp0 : cp1);
        sCol[j]  = cv;
        sCol2[j] = __fmul_rn(cv, cv);
    }
    __syncthreads();

    float m[8];
#pragma unroll
    for (int o = 0; o < 8; ++o) m[o] = INFV;

    const float* smap = seg_maps + (size_t)b * 10000;

    // ---- batched load phase: 10 coalesced float4 loads, all in flight ----
    const bool tail_ok = (tid < 196);        // quad 2304+tid valid iff tid<196
    float4 mpv[10];
#pragma unroll
    for (int u = 0; u < 10; ++u) {
        int q = tid + (u << 8);              // stride-256, coalesced
        if (u == 9 && !tail_ok) q = 2499;    // clamped in-bounds dummy address
        mpv[u] = *reinterpret_cast<const float4*>(smap + (q << 2));
    }
    if (!tail_ok) mpv[9] = make_float4(0.0f, 0.0f, 0.0f, 0.0f);  // mask -> !valid

    // ---- process phase ----
#pragma unroll
    for (int u = 0; u < 10; ++u) {
        const int q  = (u == 9 && !tail_ok) ? 2499 : (tid + (u << 8));
        const int k0 = q << 2;
        const int i  = k0 / 100;             // magic-mul divide (compile-time const divisor)
        const int j0 = k0 - i * 100;         // multiple of 4 (100 % 4 == 0)

        const float4 mp = mpv[u];
        const float  rv = sRow[i];
        const float x2r = __fmul_rn(rv, rv);
        const float4 c2 = *reinterpret_cast<const float4*>(&sCol2[j0]);

        const float mapv[4] = {mp.x, mp.y, mp.z, mp.w};
        const float c2s[4]  = {c2.x, c2.y, c2.z, c2.w};
        float d2[4];
        bool  anyp = false;
#pragma unroll
        for (int c = 0; c < 4; ++c) {
            d2[c] = __fadd_rn(x2r, c2s[c]);               // == ref's x*x + y*y
            anyp |= (mapv[c] > 0.05f) && (d2[c] <= r2m);
        }
        // Whole-wave skip: most of the map is outside the vision radius.
        if (__any(anyp)) {
            const float4 cv4 = *reinterpret_cast<const float4*>(&sCol[j0]);
            const float cvs[4] = {cv4.x, cv4.y, cv4.z, cv4.w};
#pragma unroll
            for (int c = 0; c < 4; ++c) {
                const float colv = cvs[c];
                const float x = swp ? colv : rv;
                const float y = swp ? rv : colv;
                const float dd = sqrtf(d2[c]);            // exact, as reference
                const bool val = (mapv[c] > 0.05f) && (dd <= r);
                // bin = floor(mod(atan2(x,y), 2pi) / (pi/4)), geometric form.
                const int bin =
                    (y > 0.0f)
                      ? ((x >= 0.0f) ? ((x < y) ? 0 : 1)
                                     : ((-x > y) ? 6 : 7))
                      : ((y < 0.0f)
                           ? ((x > 0.0f) ? ((x > -y) ? 2 : 3)
                                         : ((x > y) ? 4 : 5))
                           : ((x > 0.0f) ? 2
                              : ((x < 0.0f) ? 6
                                 : ((__float_as_uint(y) & 0x80000000u) ? 4 : 0))));
                const float e  = __fdividef(__fadd_rn(dd, 1.0e-8f),
                                            __fadd_rn(mapv[c], 1.0e-8f));
                const float dv = val ? e : INFV;
#pragma unroll
                for (int o = 0; o < 8; ++o)
                    m[o] = fminf(m[o], (bin == o) ? dv : INFV);
            }
        }
    }

    // wave-level min reduce, then cross-wave via LDS
#pragma unroll
    for (int o = 0; o < 8; ++o) {
        float v = m[o];
#pragma unroll
        for (int off = 32; off > 0; off >>= 1)
            v = fminf(v, __shfl_down(v, off, 64));
        if (lane == 0) sred[wave][o] = v;
    }
    __syncthreads();

    if (tid < 16) {
        float vel = 0.0f, md = 0.0f, dir = 0.0f;
        if (tid < 8) {
            const float v = fminf(fminf(sred[0][tid], sred[1][tid]),
                                  fminf(sred[2][tid], sred[3][tid]));
            if (v < INFV) {
                vel = mlen;
                md  = v;
                dir = __fmul_rn(6.28318530717958647692f,
                                __fmul_rn((float)tid + 0.5f, 0.125f));
            }
        }
        float* po = out + (size_t)b * 48 + tid * 3;
        po[0] = vel; po[1] = md; po[2] = dir;
    }
}

extern "C" void kernel_launch(void* const* d_in, const int* in_sizes, int n_in,
                              void* d_out, int out_size, void* d_ws, size_t ws_size,
                              hipStream_t stream) {
    const float* seg_maps = (const float*)d_in[0];
    const float* paras    = (const float*)d_in[1];   // (B,6): W0 W1 b0 b1 ord0 ord1
    const float* traj     = (const float*)d_in[2];   // (B,8,2)
    const float* cpos     = (const float*)d_in[3];   // (B,1,2)
    float* out            = (float*)d_out;           // (B,16,3) fp32

    const int B = in_sizes[1] / 6;
    pcl_kernel<<<B, 256, 0, stream>>>(seg_maps, paras, traj, cpos, out);
}